// Round 12
// baseline (285.102 us; speedup 1.0000x reference)
//
#include <hip/hip_runtime.h>
#include <math.h>

#define NP 512
#define TS 128
#define GI 33
#define TAB2D (GI * GI)     // 1089
#define GV 193              // V-table nodes per timestep, h = 1/192
#define V_Lc 3.4f
#define V_0c 4.2f
#define GAMMAc 0.9f
#define ALPHAc 0.15f
#define BETAc 15.0f
#define E_INV 2e-5f
#define F_STDc 0.05f
#define G_STDc 0.02f

// light barrier: LDS-ordering only, leaves global loads/stores in flight
#define LBAR() asm volatile("s_waitcnt lgkmcnt(0)\n\ts_barrier" ::: "memory")

__device__ __forceinline__ float sigmoid_jax(float x) {
    float e = expf(-fabsf(x));
    float num = (x >= 0.f) ? 1.f : e;
    return num / (1.f + e);
}

__device__ __forceinline__ float vocf(float s) {
    float sm1 = s - 1.f;
    return V_Lc + (V_0c - V_Lc) * expf(GAMMAc * sm1)
         + (ALPHAc * V_Lc) * sm1
         + (1.f - ALPHAc) * V_Lc * (expf(-BETAc) - expf(-BETAc * sqrtf(s)));
}

// ---------------- DPP cross-lane helpers --------------------------------
template <int R>
__device__ __forceinline__ int dpp_ror(int v) {
    return __builtin_amdgcn_update_dpp(0, v, 0x120 | R, 0xf, 0xf, false);
}
template <int S>
__device__ __forceinline__ int dpp_shr(int v) {
    return __builtin_amdgcn_update_dpp(0, v, 0x110 | S, 0xf, 0xf, true);
}
__device__ __forceinline__ float rdlane_f(float v, int l) {
    return __int_as_float(__builtin_amdgcn_readlane(__float_as_int(v), l));
}

__device__ __forceinline__ float wave_max_f(float v) {
    v = fmaxf(v, __int_as_float(dpp_ror<1>(__float_as_int(v))));
    v = fmaxf(v, __int_as_float(dpp_ror<2>(__float_as_int(v))));
    v = fmaxf(v, __int_as_float(dpp_ror<4>(__float_as_int(v))));
    v = fmaxf(v, __int_as_float(dpp_ror<8>(__float_as_int(v))));
    int iv = __float_as_int(v);
    v = fmaxf(v, __int_as_float(__builtin_amdgcn_update_dpp(iv, iv, 0x142, 0xf, 0xf, false))); // bcast15
    iv = __float_as_int(v);
    v = fmaxf(v, __int_as_float(__builtin_amdgcn_update_dpp(iv, iv, 0x143, 0xf, 0xf, false))); // bcast31
    return rdlane_f(v, 63);
}

__device__ __forceinline__ int wave_max_i(int v) {
    v = max(v, dpp_ror<1>(v));
    v = max(v, dpp_ror<2>(v));
    v = max(v, dpp_ror<4>(v));
    v = max(v, dpp_ror<8>(v));
    v = max(v, __builtin_amdgcn_update_dpp(v, v, 0x142, 0xf, 0xf, false));
    v = max(v, __builtin_amdgcn_update_dpp(v, v, 0x143, 0xf, 0xf, false));
    return __builtin_amdgcn_readlane(v, 63);
}

__device__ __forceinline__ float wave_scan_add(float v, int lane) {
    v += __int_as_float(dpp_shr<1>(__float_as_int(v)));
    v += __int_as_float(dpp_shr<2>(__float_as_int(v)));
    v += __int_as_float(dpp_shr<4>(__float_as_int(v)));
    v += __int_as_float(dpp_shr<8>(__float_as_int(v)));
    float s15 = rdlane_f(v, 15);
    float s31 = rdlane_f(v, 31);
    float s47 = rdlane_f(v, 47);
    int row = lane >> 4;
    if (row >= 1) v += s15;
    if (row >= 2) v += s31;
    if (row >= 3) v += s47;
    return v;
}

__device__ __forceinline__ int wave_scanmax_i(int v, int lane) {
    v = max(v, dpp_shr<1>(v));
    v = max(v, dpp_shr<2>(v));
    v = max(v, dpp_shr<4>(v));
    v = max(v, dpp_shr<8>(v));
    int r15 = __builtin_amdgcn_readlane(v, 15);
    int r31 = __builtin_amdgcn_readlane(v, 31);
    int r47 = __builtin_amdgcn_readlane(v, 47);
    int row = lane >> 4;
    if (row >= 1) v = max(v, r15);
    if (row >= 2) v = max(v, r31);
    if (row >= 3) v = max(v, r47);
    return v;
}

// cubic Lagrange on a 33-node row at value s in [0,1] (h = 1/32)
__device__ __forceinline__ float interp33(const float* __restrict__ row, float s) {
    float x = s * 32.0f;
    int j = (int)floorf(x);
    j = j < 0 ? 0 : (j > 31 ? 31 : j);
    int st = j - 1;
    st = st < 0 ? 0 : (st > 29 ? 29 : st);
    float uu = x - (float)st;
    float um0 = uu, um1 = uu - 1.f, um2 = uu - 2.f, um3 = uu - 3.f;
    float c0 = um1 * um2 * um3 * (-1.f / 6.f);
    float c1 = um0 * um2 * um3 * (0.5f);
    float c2 = um0 * um1 * um3 * (-0.5f);
    float c3 = um0 * um1 * um2 * (1.f / 6.f);
    return c0 * row[st] + c1 * row[st + 1] + c2 * row[st + 2] + c3 * row[st + 3];
}

// cubic Lagrange on a 193-node row at x = s*192 (clamped)
__device__ __forceinline__ float interp193(const float* __restrict__ row, float s) {
    float x = s * 192.0f;
    int j = (int)floorf(x);
    j = j < 0 ? 0 : (j > 191 ? 191 : j);
    int st = j - 1;
    st = st < 0 ? 0 : (st > 189 ? 189 : st);
    float uu = x - (float)st;
    float um0 = uu, um1 = uu - 1.f, um2 = uu - 2.f, um3 = uu - 3.f;
    float c0 = um1 * um2 * um3 * (-1.f / 6.f);
    float c1 = um0 * um2 * um3 * (0.5f);
    float c2 = um0 * um1 * um3 * (-0.5f);
    float c3 = um0 * um1 * um2 * (1.f / 6.f);
    return c0 * row[st] + c1 * row[st + 1] + c2 * row[st + 2] + c3 * row[st + 3];
}

// count of slots i in [0,512) with fl(i+u) <= C (+-1 fixup)
__device__ __forceinline__ int count_le(float C, float u) {
    int h = (int)floorf(C - u);
    h = h < -1 ? -1 : (h > 511 ? 511 : h);
    h += (int)((h < 511) && (((float)(h + 1) + u) <= C));
    h -= (int)((h >= 0) && (((float)h + u) > C));
    return h + 1;
}

// ---------------------------------------------------------------------------
// Phase A: 2-D table Z(s_i, I_j) on 33x33 nodes, partial dots per 256-col half.
// Grid: 138 blocks = 69 rowblocks (16 rows) x 2 colhalves. 2 rows/thread.
// Sum associations bit-identical to the R11 version.
// ---------------------------------------------------------------------------
#define BKT 32
__global__ __launch_bounds__(256) void k_tab(
    const float* __restrict__ w1, const float* __restrict__ b1,
    const float* __restrict__ w2, const float* __restrict__ b2,
    const float* __restrict__ w3, float* __restrict__ zpart)
{
    const int tid = threadIdx.x;
    const int rowblk = blockIdx.x >> 1;
    const int colhalf = blockIdx.x & 1;
    const int r0 = rowblk * 16;
    const int cbase = colhalf * 256;

    __shared__ float As[16][BKT + 1];
    __shared__ float Bs[BKT][256];
    __shared__ float srow[16], irow[16];

    if (tid < 16) {
        int r = r0 + tid;
        r = r > (TAB2D - 1) ? (TAB2D - 1) : r;
        int si = r / GI;
        int ii = r - si * GI;
        srow[tid] = (float)si * (1.0f / 32.0f);
        irow[tid] = (float)ii * (1.0f / 32.0f);
    }
    __syncthreads();

    const int rg = tid >> 5;   // 0..7 -> rows rg*2, rg*2+1
    const int ct = tid & 31;   // cols cbase + ct*4 + {0..3} + {0,128}
    float acc[2][8];
    #pragma unroll
    for (int a = 0; a < 2; ++a)
        #pragma unroll
        for (int b = 0; b < 8; ++b) acc[a][b] = 0.f;

    for (int kk = 0; kk < 1024; kk += BKT) {
        #pragma unroll
        for (int h = 0; h < 2; ++h) {
            int idx = tid + h * 256;
            int row = idx >> 5, k = idx & 31, kc = kk + k;
            float pre = srow[row] * w1[kc] + irow[row] * w1[1024 + kc] + b1[kc];
            As[row][k] = sigmoid_jax(pre);
        }
        #pragma unroll
        for (int jj = 0; jj < 8; ++jj) {
            int vi = tid + jj * 256;
            int k = vi >> 6, c4 = vi & 63;
            *(float4*)&Bs[k][c4 * 4] = *(const float4*)&w2[(kk + k) * 512 + cbase + c4 * 4];
        }
        __syncthreads();
        #pragma unroll
        for (int k = 0; k < BKT; ++k) {
            float a0 = As[rg * 2][k];
            float a1 = As[rg * 2 + 1][k];
            float bq[8];
            *(float4*)&bq[0] = *(const float4*)&Bs[k][ct * 4];
            *(float4*)&bq[4] = *(const float4*)&Bs[k][ct * 4 + 128];
            #pragma unroll
            for (int q = 0; q < 8; ++q) {
                acc[0][q] += a0 * bq[q];
                acc[1][q] += a1 * bq[q];
            }
        }
        __syncthreads();
    }

    float b2r[8], w3r[8];
    *(float4*)&b2r[0] = *(const float4*)&b2[cbase + ct * 4];
    *(float4*)&b2r[4] = *(const float4*)&b2[cbase + ct * 4 + 128];
    *(float4*)&w3r[0] = *(const float4*)&w3[cbase + ct * 4];
    *(float4*)&w3r[4] = *(const float4*)&w3[cbase + ct * 4 + 128];
    #pragma unroll
    for (int rr = 0; rr < 2; ++rr) {
        float zp = 0.f;
        #pragma unroll
        for (int q = 0; q < 8; ++q)
            zp += w3r[q] * sigmoid_jax(acc[rr][q] + b2r[q]);
        #pragma unroll
        for (int mm = 1; mm < 32; mm <<= 1) zp += __shfl_xor(zp, mm);
        if (ct == 0 && (r0 + rg * 2 + rr) < TAB2D)
            zpart[colhalf * TAB2D + r0 + rg * 2 + rr] = zp;
    }
}

// ---------------------------------------------------------------------------
// Phase B: whole filter, 1 block, 512 threads, 2 light barriers/step.
// Writes V and resampled soc DIRECTLY to out (particle-major) - no k_fin.
// ---------------------------------------------------------------------------
__global__ __launch_bounds__(512, 1) void k_seq(
    const float* __restrict__ zpart, const float* __restrict__ soc_init,
    const float* __restrict__ current, const float* __restrict__ vmeas,
    const float* __restrict__ u, const float* __restrict__ noise,
    const float* __restrict__ b3, float* __restrict__ out)
{
    const int tid = threadIdx.x;
    const int lane = tid & 63;
    const int wv = tid >> 6;

    __shared__ float vt[TS][GV];      // 98.8 KB: V_t(s) cubic tables
    __shared__ float zt[TS][GI];      // I-collapsed Z tables (preamble only)
    __shared__ float zt2d[TAB2D];     // (preamble only)
    __shared__ float vocs[GV];
    __shared__ float socs[2][NP];
    __shared__ int marker[NP];
    __shared__ float cur_s[TS], vm_s[TS], u_s[TS];
    __shared__ float redM[8], redT[8];

    // ---- preamble ----
    float bb3 = b3[0];
    for (int j = tid; j < TAB2D; j += 512) zt2d[j] = zpart[j] + zpart[TAB2D + j] + bb3;
    if (tid < TS) { cur_s[tid] = current[tid]; vm_s[tid] = vmeas[tid]; u_s[tid] = u[tid]; }
    if (tid < GV) vocs[tid] = vocf((float)tid * (1.0f / 192.0f));
    marker[tid] = 0;
    __syncthreads();
    // zt[t][g] = cubic-in-I( zt2d[g][.], I_t )
    for (int idx = tid; idx < TS * GI; idx += 512) {
        int t = idx / GI, g = idx - t * GI;
        zt[t][g] = interp33(&zt2d[g * GI], cur_s[t]);
    }
    __syncthreads();
    // vt[t][j] = voc(s_j) - I_t * Z_t(s_j),  s_j = j/192
    for (int idx = tid; idx < TS * GV; idx += 512) {
        int t = idx / GV, j = idx - t * GV;
        float sj = (float)j * (1.0f / 192.0f);
        vt[t][j] = vocs[j] - cur_s[t] * interp33(&zt[t][0], sj);
    }
    __syncthreads();

    // ---- main loop ----
    float soc = soc_init[tid];
    float Iprev = cur_s[0];
    float V = interp193(&vt[0][0], soc);
    float loss_acc = 0.f;
    const float LOG_NU = logf(19.947114020071635f);
    const float LOG_N = logf(512.f);
    float nz_cur = noise[tid];
    float* outV = out + 1 + tid * TS;
    float* outS = out + 1 + NP * TS + tid * TS;

    for (int t = 0; t < TS; ++t) {
        int tn = (t + 1 < TS) ? t + 1 : t;
        float nz_next = noise[tn * 512 + tid];   // stays in flight across LBARs

        // ---- A: propagate, V via table, logW, wave max + scan ----
        soc = soc - Iprev * V * E_INV + F_STDc * nz_cur;
        soc = soc > 1.f ? 1.f : (soc < 0.f ? 1e-10f : soc);
        socs[t & 1][tid] = soc;

        V = interp193(&vt[t][0], soc);
        float d = (V - vm_s[t]) * (1.f / G_STDc);
        float lw = LOG_NU - 0.5f * d * d;

        float m = wave_max_f(lw);
        float e = __expf(lw - m);
        float incl = wave_scan_add(e, lane);
        if (lane == 63) { redM[wv] = m; redT[wv] = incl; }
        LBAR();                                            // barrier 1

        // ---- B: lane-parallel cross-wave combine ----
        float rm = redM[lane & 7];
        float rt = redT[lane & 7];
        float M = rm;
        M = fmaxf(M, __int_as_float(dpp_ror<1>(__float_as_int(M))));
        M = fmaxf(M, __int_as_float(dpp_ror<2>(__float_as_int(M))));
        M = fmaxf(M, __int_as_float(dpp_ror<4>(__float_as_int(M))));
        M = fmaxf(M, __int_as_float(dpp_ror<8>(__float_as_int(M))));
        float fw = __expf(rm - M);
        float term = rt * fw;
        float sc = term;
        sc += __int_as_float(dpp_shr<1>(__float_as_int(sc)));
        sc += __int_as_float(dpp_shr<2>(__float_as_int(sc)));
        sc += __int_as_float(dpp_shr<4>(__float_as_int(sc)));
        float S = rdlane_f(sc, 7);
        float off = 0.f;
        if (wv > 0) off = rdlane_f(sc, wv - 1);
        float fw_own = rdlane_f(fw, wv);
        loss_acc += M + __logf(S) - LOG_N;

        float C = 512.f * ((off + incl * fw_own) / S);
        int hi = count_le(C, u_s[t]);
        if (hi < 512) atomicMax(&marker[hi], (t << 10) | (tid + 1));
        LBAR();                                            // barrier 2

        // ---- C: owner via max-scan of markers, gather, direct out stores ----
        int pm = 0;
        for (int w = 0; w < wv; ++w) pm = max(pm, marker[w * 64 + lane]);
        pm = wave_max_i(pm);
        int v = wave_scanmax_i(marker[tid], lane);
        int sv = max(v, pm);
        int owner = ((sv >> 10) == t) ? (sv & 1023) : 0;
        owner = owner > 511 ? 511 : owner;
        float socr = socs[t & 1][owner];

        outV[t] = V;                 // uncoalesced but stays in flight (LBAR)
        outS[t] = socr;
        soc = socr;
        Iprev = cur_s[t];
        nz_cur = nz_next;
    }
    if (tid == 0) out[0] = loss_acc;
}

extern "C" void kernel_launch(void* const* d_in, const int* in_sizes, int n_in,
                              void* d_out, int out_size, void* d_ws, size_t ws_size,
                              hipStream_t stream)
{
    const float* soc_init = (const float*)d_in[0];
    const float* current  = (const float*)d_in[1];
    const float* vmeas    = (const float*)d_in[2];
    const float* noise    = (const float*)d_in[3];
    const float* u        = (const float*)d_in[4];
    const float* w1 = (const float*)d_in[5];
    const float* b1 = (const float*)d_in[6];
    const float* w2 = (const float*)d_in[7];
    const float* b2 = (const float*)d_in[8];
    const float* w3 = (const float*)d_in[9];
    const float* b3 = (const float*)d_in[10];
    float* out = (float*)d_out;
    float* ws  = (float*)d_ws;

    float* zpart = ws;   // 2*TAB2D floats

    k_tab<<<138, 256, 0, stream>>>(w1, b1, w2, b2, w3, zpart);
    k_seq<<<1, 512, 0, stream>>>(zpart, soc_init, current, vmeas, u, noise, b3, out);
}

// Round 13
// 259.623 us; speedup vs baseline: 1.0981x; 1.0981x over previous
//
#include <hip/hip_runtime.h>
#include <math.h>

#define NP 512
#define TS 128
#define GI 33
#define TAB2D (GI * GI)     // 1089
#define GV 193              // V-table nodes per timestep, h = 1/192
#define V_Lc 3.4f
#define V_0c 4.2f
#define GAMMAc 0.9f
#define ALPHAc 0.15f
#define BETAc 15.0f
#define E_INV 2e-5f
#define F_STDc 0.05f
#define G_STDc 0.02f

// light barrier: LDS-ordering only, leaves global loads/stores in flight
#define LBAR() asm volatile("s_waitcnt lgkmcnt(0)\n\ts_barrier" ::: "memory")

__device__ __forceinline__ float sigmoid_jax(float x) {
    float e = expf(-fabsf(x));
    float num = (x >= 0.f) ? 1.f : e;
    return num / (1.f + e);
}

__device__ __forceinline__ float vocf(float s) {
    float sm1 = s - 1.f;
    return V_Lc + (V_0c - V_Lc) * expf(GAMMAc * sm1)
         + (ALPHAc * V_Lc) * sm1
         + (1.f - ALPHAc) * V_Lc * (expf(-BETAc) - expf(-BETAc * sqrtf(s)));
}

// ---------------- DPP cross-lane helpers --------------------------------
template <int R>
__device__ __forceinline__ int dpp_ror(int v) {
    return __builtin_amdgcn_update_dpp(0, v, 0x120 | R, 0xf, 0xf, false);
}
template <int S>
__device__ __forceinline__ int dpp_shr(int v) {
    return __builtin_amdgcn_update_dpp(0, v, 0x110 | S, 0xf, 0xf, true);
}
__device__ __forceinline__ float rdlane_f(float v, int l) {
    return __int_as_float(__builtin_amdgcn_readlane(__float_as_int(v), l));
}

__device__ __forceinline__ float wave_max_f(float v) {
    v = fmaxf(v, __int_as_float(dpp_ror<1>(__float_as_int(v))));
    v = fmaxf(v, __int_as_float(dpp_ror<2>(__float_as_int(v))));
    v = fmaxf(v, __int_as_float(dpp_ror<4>(__float_as_int(v))));
    v = fmaxf(v, __int_as_float(dpp_ror<8>(__float_as_int(v))));
    int iv = __float_as_int(v);
    v = fmaxf(v, __int_as_float(__builtin_amdgcn_update_dpp(iv, iv, 0x142, 0xf, 0xf, false))); // bcast15
    iv = __float_as_int(v);
    v = fmaxf(v, __int_as_float(__builtin_amdgcn_update_dpp(iv, iv, 0x143, 0xf, 0xf, false))); // bcast31
    return rdlane_f(v, 63);
}

__device__ __forceinline__ int wave_max_i(int v) {
    v = max(v, dpp_ror<1>(v));
    v = max(v, dpp_ror<2>(v));
    v = max(v, dpp_ror<4>(v));
    v = max(v, dpp_ror<8>(v));
    v = max(v, __builtin_amdgcn_update_dpp(v, v, 0x142, 0xf, 0xf, false));
    v = max(v, __builtin_amdgcn_update_dpp(v, v, 0x143, 0xf, 0xf, false));
    return __builtin_amdgcn_readlane(v, 63);
}

__device__ __forceinline__ float wave_scan_add(float v, int lane) {
    v += __int_as_float(dpp_shr<1>(__float_as_int(v)));
    v += __int_as_float(dpp_shr<2>(__float_as_int(v)));
    v += __int_as_float(dpp_shr<4>(__float_as_int(v)));
    v += __int_as_float(dpp_shr<8>(__float_as_int(v)));
    float s15 = rdlane_f(v, 15);
    float s31 = rdlane_f(v, 31);
    float s47 = rdlane_f(v, 47);
    int row = lane >> 4;
    if (row >= 1) v += s15;
    if (row >= 2) v += s31;
    if (row >= 3) v += s47;
    return v;
}

__device__ __forceinline__ int wave_scanmax_i(int v, int lane) {
    v = max(v, dpp_shr<1>(v));
    v = max(v, dpp_shr<2>(v));
    v = max(v, dpp_shr<4>(v));
    v = max(v, dpp_shr<8>(v));
    int r15 = __builtin_amdgcn_readlane(v, 15);
    int r31 = __builtin_amdgcn_readlane(v, 31);
    int r47 = __builtin_amdgcn_readlane(v, 47);
    int row = lane >> 4;
    if (row >= 1) v = max(v, r15);
    if (row >= 2) v = max(v, r31);
    if (row >= 3) v = max(v, r47);
    return v;
}

// cubic Lagrange on a 33-node row at value s in [0,1] (h = 1/32)
__device__ __forceinline__ float interp33(const float* __restrict__ row, float s) {
    float x = s * 32.0f;
    int j = (int)floorf(x);
    j = j < 0 ? 0 : (j > 31 ? 31 : j);
    int st = j - 1;
    st = st < 0 ? 0 : (st > 29 ? 29 : st);
    float uu = x - (float)st;
    float um0 = uu, um1 = uu - 1.f, um2 = uu - 2.f, um3 = uu - 3.f;
    float c0 = um1 * um2 * um3 * (-1.f / 6.f);
    float c1 = um0 * um2 * um3 * (0.5f);
    float c2 = um0 * um1 * um3 * (-0.5f);
    float c3 = um0 * um1 * um2 * (1.f / 6.f);
    return c0 * row[st] + c1 * row[st + 1] + c2 * row[st + 2] + c3 * row[st + 3];
}

// cubic Lagrange on a 193-node row at x = s*192 (clamped)
__device__ __forceinline__ float interp193(const float* __restrict__ row, float s) {
    float x = s * 192.0f;
    int j = (int)floorf(x);
    j = j < 0 ? 0 : (j > 191 ? 191 : j);
    int st = j - 1;
    st = st < 0 ? 0 : (st > 189 ? 189 : st);
    float uu = x - (float)st;
    float um0 = uu, um1 = uu - 1.f, um2 = uu - 2.f, um3 = uu - 3.f;
    float c0 = um1 * um2 * um3 * (-1.f / 6.f);
    float c1 = um0 * um2 * um3 * (0.5f);
    float c2 = um0 * um1 * um3 * (-0.5f);
    float c3 = um0 * um1 * um2 * (1.f / 6.f);
    return c0 * row[st] + c1 * row[st + 1] + c2 * row[st + 2] + c3 * row[st + 3];
}

// count of slots i in [0,512) with fl(i+u) <= C (+-1 fixup)
__device__ __forceinline__ int count_le(float C, float u) {
    int h = (int)floorf(C - u);
    h = h < -1 ? -1 : (h > 511 ? 511 : h);
    h += (int)((h < 511) && (((float)(h + 1) + u) <= C));
    h -= (int)((h >= 0) && (((float)h + u) > C));
    return h + 1;
}

// ---------------------------------------------------------------------------
// Phase A: 2-D table Z(s_i, I_j) on 33x33 nodes, partial dots per 256-col half.
// Grid: 138 blocks = 69 rowblocks (16 rows) x 2 colhalves. 2 rows/thread.
// ---------------------------------------------------------------------------
#define BKT 32
__global__ __launch_bounds__(256) void k_tab(
    const float* __restrict__ w1, const float* __restrict__ b1,
    const float* __restrict__ w2, const float* __restrict__ b2,
    const float* __restrict__ w3, float* __restrict__ zpart)
{
    const int tid = threadIdx.x;
    const int rowblk = blockIdx.x >> 1;
    const int colhalf = blockIdx.x & 1;
    const int r0 = rowblk * 16;
    const int cbase = colhalf * 256;

    __shared__ float As[16][BKT + 1];
    __shared__ float Bs[BKT][256];
    __shared__ float srow[16], irow[16];

    if (tid < 16) {
        int r = r0 + tid;
        r = r > (TAB2D - 1) ? (TAB2D - 1) : r;
        int si = r / GI;
        int ii = r - si * GI;
        srow[tid] = (float)si * (1.0f / 32.0f);
        irow[tid] = (float)ii * (1.0f / 32.0f);
    }
    __syncthreads();

    const int rg = tid >> 5;   // 0..7 -> rows rg*2, rg*2+1
    const int ct = tid & 31;   // cols cbase + ct*4 + {0..3} + {0,128}
    float acc[2][8];
    #pragma unroll
    for (int a = 0; a < 2; ++a)
        #pragma unroll
        for (int b = 0; b < 8; ++b) acc[a][b] = 0.f;

    for (int kk = 0; kk < 1024; kk += BKT) {
        #pragma unroll
        for (int h = 0; h < 2; ++h) {
            int idx = tid + h * 256;
            int row = idx >> 5, k = idx & 31, kc = kk + k;
            float pre = srow[row] * w1[kc] + irow[row] * w1[1024 + kc] + b1[kc];
            As[row][k] = sigmoid_jax(pre);
        }
        #pragma unroll
        for (int jj = 0; jj < 8; ++jj) {
            int vi = tid + jj * 256;
            int k = vi >> 6, c4 = vi & 63;
            *(float4*)&Bs[k][c4 * 4] = *(const float4*)&w2[(kk + k) * 512 + cbase + c4 * 4];
        }
        __syncthreads();
        #pragma unroll
        for (int k = 0; k < BKT; ++k) {
            float a0 = As[rg * 2][k];
            float a1 = As[rg * 2 + 1][k];
            float bq[8];
            *(float4*)&bq[0] = *(const float4*)&Bs[k][ct * 4];
            *(float4*)&bq[4] = *(const float4*)&Bs[k][ct * 4 + 128];
            #pragma unroll
            for (int q = 0; q < 8; ++q) {
                acc[0][q] += a0 * bq[q];
                acc[1][q] += a1 * bq[q];
            }
        }
        __syncthreads();
    }

    float b2r[8], w3r[8];
    *(float4*)&b2r[0] = *(const float4*)&b2[cbase + ct * 4];
    *(float4*)&b2r[4] = *(const float4*)&b2[cbase + ct * 4 + 128];
    *(float4*)&w3r[0] = *(const float4*)&w3[cbase + ct * 4];
    *(float4*)&w3r[4] = *(const float4*)&w3[cbase + ct * 4 + 128];
    #pragma unroll
    for (int rr = 0; rr < 2; ++rr) {
        float zp = 0.f;
        #pragma unroll
        for (int q = 0; q < 8; ++q)
            zp += w3r[q] * sigmoid_jax(acc[rr][q] + b2r[q]);
        #pragma unroll
        for (int mm = 1; mm < 32; mm <<= 1) zp += __shfl_xor(zp, mm);
        if (ct == 0 && (r0 + rg * 2 + rr) < TAB2D)
            zpart[colhalf * TAB2D + r0 + rg * 2 + rr] = zp;
    }
}

// ---------------------------------------------------------------------------
// Phase B: whole filter, 1 block, 512 threads, 2 light barriers/step.
// Coalesced time-major stores to workspace (k_fin transposes).
// ---------------------------------------------------------------------------
__global__ __launch_bounds__(512, 1) void k_seq(
    const float* __restrict__ zpart, const float* __restrict__ soc_init,
    const float* __restrict__ current, const float* __restrict__ vmeas,
    const float* __restrict__ u, const float* __restrict__ noise,
    const float* __restrict__ b3, float* __restrict__ vbuf,
    float* __restrict__ sbuf, float* __restrict__ out)
{
    const int tid = threadIdx.x;
    const int lane = tid & 63;
    const int wv = tid >> 6;

    __shared__ float vt[TS][GV];      // 98.8 KB: V_t(s) cubic tables
    __shared__ float zt[TS][GI];      // I-collapsed Z tables (preamble only)
    __shared__ float zt2d[TAB2D];     // (preamble only)
    __shared__ float vocs[GV];
    __shared__ float socs[2][NP];
    __shared__ int marker[NP];
    __shared__ float cur_s[TS], vm_s[TS], u_s[TS];
    __shared__ float2 redMT[8];       // (m, incl) packed: one b64 read after bar1

    // ---- preamble ----
    float bb3 = b3[0];
    for (int j = tid; j < TAB2D; j += 512) zt2d[j] = zpart[j] + zpart[TAB2D + j] + bb3;
    if (tid < TS) { cur_s[tid] = current[tid]; vm_s[tid] = vmeas[tid]; u_s[tid] = u[tid]; }
    if (tid < GV) vocs[tid] = vocf((float)tid * (1.0f / 192.0f));
    marker[tid] = 0;
    __syncthreads();
    // zt[t][g] = cubic-in-I( zt2d[g][.], I_t )
    for (int idx = tid; idx < TS * GI; idx += 512) {
        int t = idx / GI, g = idx - t * GI;
        zt[t][g] = interp33(&zt2d[g * GI], cur_s[t]);
    }
    __syncthreads();
    // vt[t][j] = voc(s_j) - I_t * Z_t(s_j),  s_j = j/192
    for (int idx = tid; idx < TS * GV; idx += 512) {
        int t = idx / GV, j = idx - t * GV;
        float sj = (float)j * (1.0f / 192.0f);
        vt[t][j] = vocs[j] - cur_s[t] * interp33(&zt[t][0], sj);
    }
    __syncthreads();

    // ---- main loop ----
    float soc = soc_init[tid];
    float Iprev = cur_s[0];
    float V = interp193(&vt[0][0], soc);
    float loss_acc = 0.f;
    const float LOG_NU = logf(19.947114020071635f);
    const float LOG_N = logf(512.f);
    float nz_cur = noise[tid];

    for (int t = 0; t < TS; ++t) {
        int tn = (t + 1 < TS) ? t + 1 : t;
        float nz_next = noise[tn * 512 + tid];   // stays in flight across LBARs

        // ---- A: propagate, V via table, logW, wave max + scan ----
        soc = soc - Iprev * V * E_INV + F_STDc * nz_cur;
        soc = soc > 1.f ? 1.f : (soc < 0.f ? 1e-10f : soc);
        socs[t & 1][tid] = soc;

        V = interp193(&vt[t][0], soc);
        vbuf[t * 512 + tid] = V;                 // coalesced, stays in flight
        float d = (V - vm_s[t]) * (1.f / G_STDc);
        float lw = LOG_NU - 0.5f * d * d;

        float m = wave_max_f(lw);
        float e = __expf(lw - m);
        float incl = wave_scan_add(e, lane);
        if (lane == 63) redMT[wv] = make_float2(m, incl);
        LBAR();                                            // barrier 1

        // ---- B: lane-parallel cross-wave combine ----
        float2 rmt = redMT[lane & 7];
        float rm = rmt.x;
        float rt = rmt.y;
        float M = rm;   // 8-periodic data in 16-lane row: ror 1,2,4 covers all 8
        M = fmaxf(M, __int_as_float(dpp_ror<1>(__float_as_int(M))));
        M = fmaxf(M, __int_as_float(dpp_ror<2>(__float_as_int(M))));
        M = fmaxf(M, __int_as_float(dpp_ror<4>(__float_as_int(M))));
        float fw = __expf(rm - M);
        float term = rt * fw;
        float sc = term;
        sc += __int_as_float(dpp_shr<1>(__float_as_int(sc)));
        sc += __int_as_float(dpp_shr<2>(__float_as_int(sc)));
        sc += __int_as_float(dpp_shr<4>(__float_as_int(sc)));
        float S = rdlane_f(sc, 7);
        float off = 0.f;
        if (wv > 0) off = rdlane_f(sc, wv - 1);
        float fw_own = rdlane_f(fw, wv);
        loss_acc += M + __logf(S) - LOG_N;

        float C = 512.f * ((off + incl * fw_own) / S);
        int hi = count_le(C, u_s[t]);
        if (hi < 512) atomicMax(&marker[hi], (t << 10) | (tid + 1));
        LBAR();                                            // barrier 2

        // ---- C: owner via max-scan of markers, gather, coalesced stores ----
        int pm = 0;
        for (int w = 0; w < wv; ++w) pm = max(pm, marker[w * 64 + lane]);
        pm = wave_max_i(pm);
        int v = wave_scanmax_i(marker[tid], lane);
        int sv = max(v, pm);
        int owner = ((sv >> 10) == t) ? (sv & 1023) : 0;
        owner = owner > 511 ? 511 : owner;
        float socr = socs[t & 1][owner];

        sbuf[t * 512 + tid] = socr;              // coalesced, stays in flight
        soc = socr;
        Iprev = cur_s[t];
        nz_cur = nz_next;
    }
    if (tid == 0) out[0] = loss_acc;
}

// ---------------------------------------------------------------------------
// Phase C: transpose time-major [128][512] -> particle-major [512][128]
// ---------------------------------------------------------------------------
__global__ __launch_bounds__(256) void k_fin(
    const float* __restrict__ vbuf, const float* __restrict__ sbuf,
    float* __restrict__ out)
{
    __shared__ float tile[32][33];
    int tz = blockIdx.z;
    int t0 = blockIdx.x * 32;
    int i0 = blockIdx.y * 32;
    const float* src = tz ? sbuf : vbuf;
    float* dst = out + 1 + tz * (NP * TS);
    int tx = threadIdx.x & 31, ty = threadIdx.x >> 5;
    #pragma unroll
    for (int m2 = 0; m2 < 4; ++m2)
        tile[ty + 8 * m2][tx] = src[(t0 + ty + 8 * m2) * 512 + i0 + tx];
    __syncthreads();
    #pragma unroll
    for (int m2 = 0; m2 < 4; ++m2)
        dst[(i0 + ty + 8 * m2) * 128 + t0 + tx] = tile[tx][ty + 8 * m2];
}

extern "C" void kernel_launch(void* const* d_in, const int* in_sizes, int n_in,
                              void* d_out, int out_size, void* d_ws, size_t ws_size,
                              hipStream_t stream)
{
    const float* soc_init = (const float*)d_in[0];
    const float* current  = (const float*)d_in[1];
    const float* vmeas    = (const float*)d_in[2];
    const float* noise    = (const float*)d_in[3];
    const float* u        = (const float*)d_in[4];
    const float* w1 = (const float*)d_in[5];
    const float* b1 = (const float*)d_in[6];
    const float* w2 = (const float*)d_in[7];
    const float* b2 = (const float*)d_in[8];
    const float* w3 = (const float*)d_in[9];
    const float* b3 = (const float*)d_in[10];
    float* out = (float*)d_out;
    float* ws  = (float*)d_ws;

    float* zpart = ws;                         // 2*TAB2D = 2178 floats
    float* vbuf  = ws + 2180;                  // 65536 floats (16B aligned)
    float* sbuf  = vbuf + NP * TS;             // 65536 floats

    k_tab<<<138, 256, 0, stream>>>(w1, b1, w2, b2, w3, zpart);
    k_seq<<<1, 512, 0, stream>>>(zpart, soc_init, current, vmeas, u, noise, b3,
                                 vbuf, sbuf, out);
    k_fin<<<dim3(4, 16, 2), 256, 0, stream>>>(vbuf, sbuf, out);
}

// Round 14
// 245.176 us; speedup vs baseline: 1.1628x; 1.0589x over previous
//
#include <hip/hip_runtime.h>
#include <math.h>

#define NP 512
#define TS 128
#define GI 33
#define TAB2D (GI * GI)     // 1089
#define GV 193              // V-table nodes per timestep, h = 1/192
#define V_Lc 3.4f
#define V_0c 4.2f
#define GAMMAc 0.9f
#define ALPHAc 0.15f
#define BETAc 15.0f
#define E_INV 2e-5f
#define F_STDc 0.05f
#define G_STDc 0.02f

// light barrier: LDS-ordering only, leaves global loads/stores in flight
#define LBAR() asm volatile("s_waitcnt lgkmcnt(0)\n\ts_barrier" ::: "memory")

__device__ __forceinline__ float sigmoid_jax(float x) {
    float e = expf(-fabsf(x));
    float num = (x >= 0.f) ? 1.f : e;
    return num / (1.f + e);
}

__device__ __forceinline__ float vocf(float s) {
    float sm1 = s - 1.f;
    return V_Lc + (V_0c - V_Lc) * expf(GAMMAc * sm1)
         + (ALPHAc * V_Lc) * sm1
         + (1.f - ALPHAc) * V_Lc * (expf(-BETAc) - expf(-BETAc * sqrtf(s)));
}

// ---------------- DPP cross-lane helpers --------------------------------
template <int R>
__device__ __forceinline__ int dpp_ror(int v) {
    return __builtin_amdgcn_update_dpp(0, v, 0x120 | R, 0xf, 0xf, false);
}
template <int S>
__device__ __forceinline__ int dpp_shr(int v) {
    return __builtin_amdgcn_update_dpp(0, v, 0x110 | S, 0xf, 0xf, true);
}
__device__ __forceinline__ float rdlane_f(float v, int l) {
    return __int_as_float(__builtin_amdgcn_readlane(__float_as_int(v), l));
}

__device__ __forceinline__ float wave_max_f(float v) {
    v = fmaxf(v, __int_as_float(dpp_ror<1>(__float_as_int(v))));
    v = fmaxf(v, __int_as_float(dpp_ror<2>(__float_as_int(v))));
    v = fmaxf(v, __int_as_float(dpp_ror<4>(__float_as_int(v))));
    v = fmaxf(v, __int_as_float(dpp_ror<8>(__float_as_int(v))));
    int iv = __float_as_int(v);
    v = fmaxf(v, __int_as_float(__builtin_amdgcn_update_dpp(iv, iv, 0x142, 0xf, 0xf, false))); // bcast15
    iv = __float_as_int(v);
    v = fmaxf(v, __int_as_float(__builtin_amdgcn_update_dpp(iv, iv, 0x143, 0xf, 0xf, false))); // bcast31
    return rdlane_f(v, 63);
}

__device__ __forceinline__ int wave_max_i(int v) {
    v = max(v, dpp_ror<1>(v));
    v = max(v, dpp_ror<2>(v));
    v = max(v, dpp_ror<4>(v));
    v = max(v, dpp_ror<8>(v));
    v = max(v, __builtin_amdgcn_update_dpp(v, v, 0x142, 0xf, 0xf, false));
    v = max(v, __builtin_amdgcn_update_dpp(v, v, 0x143, 0xf, 0xf, false));
    return __builtin_amdgcn_readlane(v, 63);
}

__device__ __forceinline__ float wave_scan_add(float v, int lane) {
    v += __int_as_float(dpp_shr<1>(__float_as_int(v)));
    v += __int_as_float(dpp_shr<2>(__float_as_int(v)));
    v += __int_as_float(dpp_shr<4>(__float_as_int(v)));
    v += __int_as_float(dpp_shr<8>(__float_as_int(v)));
    float s15 = rdlane_f(v, 15);
    float s31 = rdlane_f(v, 31);
    float s47 = rdlane_f(v, 47);
    int row = lane >> 4;
    if (row >= 1) v += s15;
    if (row >= 2) v += s31;
    if (row >= 3) v += s47;
    return v;
}

__device__ __forceinline__ int wave_scanmax_i(int v, int lane) {
    v = max(v, dpp_shr<1>(v));
    v = max(v, dpp_shr<2>(v));
    v = max(v, dpp_shr<4>(v));
    v = max(v, dpp_shr<8>(v));
    int r15 = __builtin_amdgcn_readlane(v, 15);
    int r31 = __builtin_amdgcn_readlane(v, 31);
    int r47 = __builtin_amdgcn_readlane(v, 47);
    int row = lane >> 4;
    if (row >= 1) v = max(v, r15);
    if (row >= 2) v = max(v, r31);
    if (row >= 3) v = max(v, r47);
    return v;
}

// cubic Lagrange on a 33-node row at value s in [0,1] (h = 1/32)
__device__ __forceinline__ float interp33(const float* __restrict__ row, float s) {
    float x = s * 32.0f;
    int j = (int)floorf(x);
    j = j < 0 ? 0 : (j > 31 ? 31 : j);
    int st = j - 1;
    st = st < 0 ? 0 : (st > 29 ? 29 : st);
    float uu = x - (float)st;
    float um0 = uu, um1 = uu - 1.f, um2 = uu - 2.f, um3 = uu - 3.f;
    float c0 = um1 * um2 * um3 * (-1.f / 6.f);
    float c1 = um0 * um2 * um3 * (0.5f);
    float c2 = um0 * um1 * um3 * (-0.5f);
    float c3 = um0 * um1 * um2 * (1.f / 6.f);
    return c0 * row[st] + c1 * row[st + 1] + c2 * row[st + 2] + c3 * row[st + 3];
}

// cubic Lagrange on a 193-node row at x = s*192 (clamped)
__device__ __forceinline__ float interp193(const float* __restrict__ row, float s) {
    float x = s * 192.0f;
    int j = (int)floorf(x);
    j = j < 0 ? 0 : (j > 191 ? 191 : j);
    int st = j - 1;
    st = st < 0 ? 0 : (st > 189 ? 189 : st);
    float uu = x - (float)st;
    float um0 = uu, um1 = uu - 1.f, um2 = uu - 2.f, um3 = uu - 3.f;
    float c0 = um1 * um2 * um3 * (-1.f / 6.f);
    float c1 = um0 * um2 * um3 * (0.5f);
    float c2 = um0 * um1 * um3 * (-0.5f);
    float c3 = um0 * um1 * um2 * (1.f / 6.f);
    return c0 * row[st] + c1 * row[st + 1] + c2 * row[st + 2] + c3 * row[st + 3];
}

// count of slots i in [0,512) with fl(i+u) <= C (+-1 fixup)
__device__ __forceinline__ int count_le(float C, float u) {
    int h = (int)floorf(C - u);
    h = h < -1 ? -1 : (h > 511 ? 511 : h);
    h += (int)((h < 511) && (((float)(h + 1) + u) <= C));
    h -= (int)((h >= 0) && (((float)h + u) > C));
    return h + 1;
}

// ---------------------------------------------------------------------------
// Phase A: 2-D table Z(s_i, I_j) on 33x33 nodes, partial dots per 256-col half.
// Grid: 138 blocks = 69 rowblocks (16 rows) x 2 colhalves. 2 rows/thread.
// (verbatim R13)
// ---------------------------------------------------------------------------
#define BKT 32
__global__ __launch_bounds__(256) void k_tab(
    const float* __restrict__ w1, const float* __restrict__ b1,
    const float* __restrict__ w2, const float* __restrict__ b2,
    const float* __restrict__ w3, float* __restrict__ zpart)
{
    const int tid = threadIdx.x;
    const int rowblk = blockIdx.x >> 1;
    const int colhalf = blockIdx.x & 1;
    const int r0 = rowblk * 16;
    const int cbase = colhalf * 256;

    __shared__ float As[16][BKT + 1];
    __shared__ float Bs[BKT][256];
    __shared__ float srow[16], irow[16];

    if (tid < 16) {
        int r = r0 + tid;
        r = r > (TAB2D - 1) ? (TAB2D - 1) : r;
        int si = r / GI;
        int ii = r - si * GI;
        srow[tid] = (float)si * (1.0f / 32.0f);
        irow[tid] = (float)ii * (1.0f / 32.0f);
    }
    __syncthreads();

    const int rg = tid >> 5;   // 0..7 -> rows rg*2, rg*2+1
    const int ct = tid & 31;   // cols cbase + ct*4 + {0..3} + {0,128}
    float acc[2][8];
    #pragma unroll
    for (int a = 0; a < 2; ++a)
        #pragma unroll
        for (int b = 0; b < 8; ++b) acc[a][b] = 0.f;

    for (int kk = 0; kk < 1024; kk += BKT) {
        #pragma unroll
        for (int h = 0; h < 2; ++h) {
            int idx = tid + h * 256;
            int row = idx >> 5, k = idx & 31, kc = kk + k;
            float pre = srow[row] * w1[kc] + irow[row] * w1[1024 + kc] + b1[kc];
            As[row][k] = sigmoid_jax(pre);
        }
        #pragma unroll
        for (int jj = 0; jj < 8; ++jj) {
            int vi = tid + jj * 256;
            int k = vi >> 6, c4 = vi & 63;
            *(float4*)&Bs[k][c4 * 4] = *(const float4*)&w2[(kk + k) * 512 + cbase + c4 * 4];
        }
        __syncthreads();
        #pragma unroll
        for (int k = 0; k < BKT; ++k) {
            float a0 = As[rg * 2][k];
            float a1 = As[rg * 2 + 1][k];
            float bq[8];
            *(float4*)&bq[0] = *(const float4*)&Bs[k][ct * 4];
            *(float4*)&bq[4] = *(const float4*)&Bs[k][ct * 4 + 128];
            #pragma unroll
            for (int q = 0; q < 8; ++q) {
                acc[0][q] += a0 * bq[q];
                acc[1][q] += a1 * bq[q];
            }
        }
        __syncthreads();
    }

    float b2r[8], w3r[8];
    *(float4*)&b2r[0] = *(const float4*)&b2[cbase + ct * 4];
    *(float4*)&b2r[4] = *(const float4*)&b2[cbase + ct * 4 + 128];
    *(float4*)&w3r[0] = *(const float4*)&w3[cbase + ct * 4];
    *(float4*)&w3r[4] = *(const float4*)&w3[cbase + ct * 4 + 128];
    #pragma unroll
    for (int rr = 0; rr < 2; ++rr) {
        float zp = 0.f;
        #pragma unroll
        for (int q = 0; q < 8; ++q)
            zp += w3r[q] * sigmoid_jax(acc[rr][q] + b2r[q]);
        #pragma unroll
        for (int mm = 1; mm < 32; mm <<= 1) zp += __shfl_xor(zp, mm);
        if (ct == 0 && (r0 + rg * 2 + rr) < TAB2D)
            zpart[colhalf * TAB2D + r0 + rg * 2 + rr] = zp;
    }
}

// ---------------------------------------------------------------------------
// Phase A2: build vt[t][193] tables in parallel (128 blocks, one per t).
// Bit-identical formulas to the R13 in-kernel preamble.
// ---------------------------------------------------------------------------
__global__ __launch_bounds__(256) void k_pre(
    const float* __restrict__ zpart, const float* __restrict__ current,
    const float* __restrict__ b3, float* __restrict__ vt_g)
{
    __shared__ float zrow[GI];
    const int t = blockIdx.x;
    const int tid = threadIdx.x;
    const float It = current[t];
    const float bb3 = b3[0];

    if (tid < GI) {
        // zrow[g] = interp33 over I of (zpart[g][.]+zpart2[g][.]+b3) at It
        float x = It * 32.0f;
        int j = (int)floorf(x);
        j = j < 0 ? 0 : (j > 31 ? 31 : j);
        int st = j - 1;
        st = st < 0 ? 0 : (st > 29 ? 29 : st);
        float uu = x - (float)st;
        float um0 = uu, um1 = uu - 1.f, um2 = uu - 2.f, um3 = uu - 3.f;
        float c0 = um1 * um2 * um3 * (-1.f / 6.f);
        float c1 = um0 * um2 * um3 * (0.5f);
        float c2 = um0 * um1 * um3 * (-0.5f);
        float c3 = um0 * um1 * um2 * (1.f / 6.f);
        int base = tid * GI + st;
        float n0 = zpart[base]     + zpart[TAB2D + base]     + bb3;
        float n1 = zpart[base + 1] + zpart[TAB2D + base + 1] + bb3;
        float n2 = zpart[base + 2] + zpart[TAB2D + base + 2] + bb3;
        float n3 = zpart[base + 3] + zpart[TAB2D + base + 3] + bb3;
        zrow[tid] = c0 * n0 + c1 * n1 + c2 * n2 + c3 * n3;
    }
    __syncthreads();
    if (tid < GV) {
        float sj = (float)tid * (1.0f / 192.0f);
        vt_g[t * GV + tid] = vocf(sj) - It * interp33(zrow, sj);
    }
}

// ---------------------------------------------------------------------------
// Phase B: whole filter, 1 block, 256 threads (4 waves, 2 particles/lane),
// 2 light barriers/step, marker-based resample.
// ---------------------------------------------------------------------------
__global__ __launch_bounds__(256, 1) void k_seq(
    const float* __restrict__ vt_g, const float* __restrict__ soc_init,
    const float* __restrict__ current, const float* __restrict__ vmeas,
    const float* __restrict__ u, const float* __restrict__ noise,
    float* __restrict__ vbuf, float* __restrict__ sbuf, float* __restrict__ out)
{
    const int tid = threadIdx.x;
    const int lane = tid & 63;
    const int wv = tid >> 6;          // 0..3

    __shared__ __align__(16) float vt[TS * GV];   // 98.8 KB
    __shared__ float2 socs2[2][NP / 2];
    __shared__ int2  marker2[NP / 2];
    __shared__ float cur_s[TS], vm_s[TS], u_s[TS];
    __shared__ float2 redMT[4];
    int* marker = (int*)marker2;

    // ---- preamble: stream tables in ----
    for (int i4 = tid; i4 < (TS * GV) / 4; i4 += 256)
        *(float4*)&vt[i4 * 4] = *(const float4*)&vt_g[i4 * 4];
    if (tid < TS) { cur_s[tid] = current[tid]; vm_s[tid] = vmeas[tid]; u_s[tid] = u[tid]; }
    marker2[tid] = make_int2(0, 0);
    __syncthreads();

    float2 si2 = *(const float2*)&soc_init[2 * tid];
    float soc0 = si2.x, soc1 = si2.y;
    float Iprev = cur_s[0];
    float V0 = interp193(&vt[0], soc0);
    float V1 = interp193(&vt[0], soc1);
    float loss_acc = 0.f;
    const float LOG_NU = logf(19.947114020071635f);
    const float LOG_N = logf(512.f);
    float2 nz = *(const float2*)&noise[2 * tid];

    for (int t = 0; t < TS; ++t) {
        int tn = (t + 1 < TS) ? t + 1 : t;
        float2 nz_next = *(const float2*)&noise[tn * 512 + 2 * tid];  // in flight

        // ---- A: propagate both particles, V, logW, wave max + pair scan ----
        soc0 = soc0 - Iprev * V0 * E_INV + F_STDc * nz.x;
        soc1 = soc1 - Iprev * V1 * E_INV + F_STDc * nz.y;
        soc0 = soc0 > 1.f ? 1.f : (soc0 < 0.f ? 1e-10f : soc0);
        soc1 = soc1 > 1.f ? 1.f : (soc1 < 0.f ? 1e-10f : soc1);
        socs2[t & 1][tid] = make_float2(soc0, soc1);

        const float* vr = &vt[t * GV];
        V0 = interp193(vr, soc0);
        V1 = interp193(vr, soc1);
        *(float2*)&vbuf[t * 512 + 2 * tid] = make_float2(V0, V1);   // coalesced
        float vm = vm_s[t];
        float d0 = (V0 - vm) * (1.f / G_STDc);
        float d1 = (V1 - vm) * (1.f / G_STDc);
        float lw0 = LOG_NU - 0.5f * d0 * d0;
        float lw1 = LOG_NU - 0.5f * d1 * d1;

        float m = wave_max_f(fmaxf(lw0, lw1));
        float e0 = __expf(lw0 - m);
        float e1 = __expf(lw1 - m);
        float ps = wave_scan_add(e0 + e1, lane);   // inclusive pair scan
        if (lane == 63) redMT[wv] = make_float2(m, ps);
        LBAR();                                            // barrier 1

        // ---- B: 4-wave combine ----
        float2 rmt = redMT[lane & 3];
        float rm = rmt.x;
        float rt = rmt.y;
        float M = rm;   // 4-periodic in 16-lane row: ror 1,2 covers all 4
        M = fmaxf(M, __int_as_float(dpp_ror<1>(__float_as_int(M))));
        M = fmaxf(M, __int_as_float(dpp_ror<2>(__float_as_int(M))));
        float fw = __expf(rm - M);
        float term = rt * fw;
        float sc = term;
        sc += __int_as_float(dpp_shr<1>(__float_as_int(sc)));
        sc += __int_as_float(dpp_shr<2>(__float_as_int(sc)));
        float S = rdlane_f(sc, 3);
        float off = (wv > 0) ? rdlane_f(sc, wv - 1) : 0.f;
        float fw_own = rdlane_f(fw, wv);
        loss_acc += M + __logf(S) - LOG_N;

        float incl1 = ps;
        float incl0 = ps - e1;
        float C0 = 512.f * ((off + incl0 * fw_own) / S);
        float C1 = 512.f * ((off + incl1 * fw_own) / S);
        float ut = u_s[t];
        int hi0 = count_le(C0, ut);
        int hi1 = count_le(C1, ut);
        if (hi0 < 512) atomicMax(&marker[hi0], (t << 10) | (2 * tid + 1));
        if (hi1 < 512) atomicMax(&marker[hi1], (t << 10) | (2 * tid + 2));
        LBAR();                                            // barrier 2

        // ---- C: owner via pair scanmax of markers, gather, stores ----
        int2 mk = marker2[tid];
        int pm_l = 0;
        for (int w = 0; w < wv; ++w) {
            int2 q = marker2[w * 64 + lane];
            pm_l = max(pm_l, max(q.x, q.y));
        }
        int pm = wave_max_i(pm_l);
        int mpair = max(mk.x, mk.y);
        int psx = wave_scanmax_i(mpair, lane);
        int up = dpp_shr<1>(psx);
        int r15 = __builtin_amdgcn_readlane(psx, 15);
        int r31 = __builtin_amdgcn_readlane(psx, 31);
        int r47 = __builtin_amdgcn_readlane(psx, 47);
        if (lane == 16) up = r15;
        if (lane == 32) up = r31;
        if (lane == 48) up = r47;   // lane 0: up = 0 from bound_ctrl
        int excl = max(up, pm);
        int tag0 = max(excl, mk.x);
        int tag1 = max(excl, mpair);
        int o0 = ((tag0 >> 10) == t) ? (tag0 & 1023) : 0;
        int o1 = ((tag1 >> 10) == t) ? (tag1 & 1023) : 0;
        o0 = o0 > 511 ? 511 : o0;
        o1 = o1 > 511 ? 511 : o1;
        const float* sflat = (const float*)&socs2[t & 1][0];
        float sr0 = sflat[o0];
        float sr1 = sflat[o1];
        *(float2*)&sbuf[t * 512 + 2 * tid] = make_float2(sr0, sr1);  // coalesced

        soc0 = sr0;
        soc1 = sr1;
        Iprev = cur_s[t];
        nz = nz_next;
    }
    if (tid == 0) out[0] = loss_acc;
}

// ---------------------------------------------------------------------------
// Phase C: transpose time-major [128][512] -> particle-major [512][128]
// ---------------------------------------------------------------------------
__global__ __launch_bounds__(256) void k_fin(
    const float* __restrict__ vbuf, const float* __restrict__ sbuf,
    float* __restrict__ out)
{
    __shared__ float tile[32][33];
    int tz = blockIdx.z;
    int t0 = blockIdx.x * 32;
    int i0 = blockIdx.y * 32;
    const float* src = tz ? sbuf : vbuf;
    float* dst = out + 1 + tz * (NP * TS);
    int tx = threadIdx.x & 31, ty = threadIdx.x >> 5;
    #pragma unroll
    for (int m2 = 0; m2 < 4; ++m2)
        tile[ty + 8 * m2][tx] = src[(t0 + ty + 8 * m2) * 512 + i0 + tx];
    __syncthreads();
    #pragma unroll
    for (int m2 = 0; m2 < 4; ++m2)
        dst[(i0 + ty + 8 * m2) * 128 + t0 + tx] = tile[tx][ty + 8 * m2];
}

extern "C" void kernel_launch(void* const* d_in, const int* in_sizes, int n_in,
                              void* d_out, int out_size, void* d_ws, size_t ws_size,
                              hipStream_t stream)
{
    const float* soc_init = (const float*)d_in[0];
    const float* current  = (const float*)d_in[1];
    const float* vmeas    = (const float*)d_in[2];
    const float* noise    = (const float*)d_in[3];
    const float* u        = (const float*)d_in[4];
    const float* w1 = (const float*)d_in[5];
    const float* b1 = (const float*)d_in[6];
    const float* w2 = (const float*)d_in[7];
    const float* b2 = (const float*)d_in[8];
    const float* w3 = (const float*)d_in[9];
    const float* b3 = (const float*)d_in[10];
    float* out = (float*)d_out;
    float* ws  = (float*)d_ws;

    float* zpart = ws;                         // 2*TAB2D = 2178 floats
    float* vt_g  = ws + 2180;                  // 24704 floats (16B aligned)
    float* vbuf  = vt_g + TS * GV;             // 65536 floats
    float* sbuf  = vbuf + NP * TS;             // 65536 floats

    k_tab<<<138, 256, 0, stream>>>(w1, b1, w2, b2, w3, zpart);
    k_pre<<<128, 256, 0, stream>>>(zpart, current, b3, vt_g);
    k_seq<<<1, 256, 0, stream>>>(vt_g, soc_init, current, vmeas, u, noise,
                                 vbuf, sbuf, out);
    k_fin<<<dim3(4, 16, 2), 256, 0, stream>>>(vbuf, sbuf, out);
}